// Round 15
// baseline (198.632 us; speedup 1.0000x reference)
//
#include <hip/hip_runtime.h>
#include <hip/hip_bf16.h>

typedef __attribute__((ext_vector_type(8))) short short8;
typedef __attribute__((ext_vector_type(4))) short short4v;
typedef __attribute__((ext_vector_type(4))) float f32x4;

#define DIM    1024
#define NHEADS 16
#define HDIM   64
#define SEQ    2048
#define BATCH  4
#define ROWS   8192            // BATCH*SEQ
#define QKV_N  3072            // 3*DIM

// 0.125 * log2(e): folds attention scale AND exp->exp2 conversion into Q
#define QSCALE_LOG2E 0.18033688011112042f

__device__ __forceinline__ unsigned short f2bf(float f) {
    union { float f; unsigned u; } v; v.f = f;
    unsigned u = v.u;
    return (unsigned short)((u + 0x7fffu + ((u >> 16) & 1u)) >> 16);   // RNE
}
__device__ __forceinline__ float exp2_fast(float x) {                // v_exp_f32 = 2^x
    float r;
    asm("v_exp_f32 %0, %1" : "=v"(r) : "v"(x));
    return r;
}
// packed f32x2 -> bf16x2 (lo = a, hi = b); no builtin on gfx950 (T12)
__device__ __forceinline__ unsigned cvt_pk_bf16(float a, float b) {
    unsigned r;
    asm("v_cvt_pk_bf16_f32 %0, %1, %2" : "=v"(r) : "v"(a), "v"(b));
    return r;
}

// async global->LDS, 16B per lane; LDS dest = wave-uniform base + lane*16
__device__ __forceinline__ void gload16(const void* g, void* l) {
    __builtin_amdgcn_global_load_lds(
        (const __attribute__((address_space(1))) unsigned int*)g,
        (__attribute__((address_space(3))) unsigned int*)l, 16, 0, 0);
}

#define MFMA16(a, b, c) __builtin_amdgcn_mfma_f32_16x16x32_bf16(a, b, c, 0, 0, 0)

// ---------------------------------------------------------------------------
// convert fp32 -> bf16 (flat)
// ---------------------------------------------------------------------------
__global__ __launch_bounds__(256)
void conv_kernel(const float* __restrict__ src, unsigned short* __restrict__ dst, int n4)
{
    const int i = blockIdx.x * 256 + threadIdx.x;
    if (i >= n4) return;
    const float4 v = ((const float4*)src)[i];
    short4v o;
    o[0] = (short)f2bf(v.x); o[1] = (short)f2bf(v.y);
    o[2] = (short)f2bf(v.z); o[3] = (short)f2bf(v.w);
    ((short4v*)dst)[i] = o;
}

// ---------------------------------------------------------------------------
// transpose + convert: src [R][C] fp32 -> dst [C][R] bf16
// ---------------------------------------------------------------------------
__global__ __launch_bounds__(256)
void convT_kernel(const float* __restrict__ src, unsigned short* __restrict__ dst,
                  int R, int C)
{
    __shared__ float T[32][33];
    const int r0 = blockIdx.y * 32, c0 = blockIdx.x * 32;
    const int tc = threadIdx.x & 31, tr = threadIdx.x >> 5;   // 32 x 8
    #pragma unroll
    for (int i = 0; i < 4; ++i)
        T[tr + i * 8][tc] = src[(size_t)(r0 + tr + i * 8) * C + c0 + tc];
    __syncthreads();
    #pragma unroll
    for (int i = 0; i < 4; ++i)
        dst[(size_t)(c0 + tr + i * 8) * R + r0 + tc] = f2bf(T[tc][tr + i * 8]);
}

// ---------------------------------------------------------------------------
// bf16 MFMA GEMM: C[M,N] = A[M,K] @ BT[N,K]^T (+bias). 128x128 tile, BK=64
// as dual 32-col buffers (m97-proven conflict-free tiling). K-STAGGER: each
// block walks the 16-step K-ring from its own offset (fp32 acc commutes) so
// co-resident blocks desync -> one block's staging overlaps another's MFMA.
// ---------------------------------------------------------------------------
template<bool WITH_BIAS, bool QSCALE>
__global__ __launch_bounds__(256)
void gemm_kernel(const unsigned short* __restrict__ A,   // [M][K] bf16
                 const unsigned short* __restrict__ BT,  // [N][K] bf16
                 const float* __restrict__ bias,
                 void* __restrict__ Cp, int M, int N, int K)
{
    __shared__ alignas(16) unsigned short LA[2][128][32];
    __shared__ alignas(16) unsigned short LB[2][128][32];

    const int tid  = threadIdx.x;
    const int lane = tid & 63;
    const int w    = tid >> 6;
    const int wr   = w >> 1, wc = w & 1;
    const int bm   = blockIdx.y * 128, bn = blockIdx.x * 128;
    const int r16  = lane & 15, g = lane >> 4;

    f32x4 acc[4][4] = {};

    const int srow = lane >> 2, skg = (lane & 3) * 8;
    const int nk   = K >> 6;                       // 16 for K=1024
    const int kph  = (blockIdx.x + blockIdx.y * 5) & (nk - 1);

    for (int t = 0; t < nk; ++t) {
        const int k0 = ((t + kph) & (nk - 1)) << 6;
        #pragma unroll
        for (int c = 0; c < 2; ++c) {
            const int chunk = w * 2 + c;            // 8 chunks over 4 waves
            const unsigned short* arow = A  + (size_t)(bm + chunk * 16 + srow) * K + k0 + skg;
            const unsigned short* brow = BT + (size_t)(bn + chunk * 16 + srow) * K + k0 + skg;
            gload16(arow,      &LA[0][chunk * 16][0]);
            gload16(arow + 32, &LA[1][chunk * 16][0]);
            gload16(brow,      &LB[0][chunk * 16][0]);
            gload16(brow + 32, &LB[1][chunk * 16][0]);
        }
        __syncthreads();
        #pragma unroll
        for (int kk = 0; kk < 2; ++kk) {
            short8 af[4], bf_[4];
            #pragma unroll
            for (int i = 0; i < 4; ++i) {
                af[i]  = *(const short8*)&LA[kk][wr * 64 + i * 16 + r16][g * 8];
                bf_[i] = *(const short8*)&LB[kk][wc * 64 + i * 16 + r16][g * 8];
            }
            __builtin_amdgcn_s_setprio(1);
            #pragma unroll
            for (int mi = 0; mi < 4; ++mi)
                #pragma unroll
                for (int ni = 0; ni < 4; ++ni)
                    acc[mi][ni] = MFMA16(af[mi], bf_[ni], acc[mi][ni]);
            __builtin_amdgcn_s_setprio(0);
        }
        __syncthreads();
    }

    #pragma unroll
    for (int mi = 0; mi < 4; ++mi)
        #pragma unroll
        for (int ni = 0; ni < 4; ++ni) {
            const int gcol = bn + wc * 64 + ni * 16 + r16;
            #pragma unroll
            for (int j = 0; j < 4; ++j) {
                const int grow = bm + wr * 64 + mi * 16 + g * 4 + j;
                float v = acc[mi][ni][j];
                if (QSCALE && gcol < DIM) v *= QSCALE_LOG2E;
                if (WITH_BIAS)
                    ((float*)Cp)[(size_t)grow * N + gcol] = v + bias[gcol];
                else
                    ((unsigned short*)Cp)[(size_t)grow * N + gcol] = f2bf(v);
            }
        }
}

// ---------------------------------------------------------------------------
// MFMA flash attention, SWAPPED-operand form, exp2-domain FIXED-SHIFT softmax
// (r13). Round-15: TILE-STAGGER — r13's fixed shift makes K-tiles fully
// order-independent (no online-max state; oacc/l accumulation commutes), so
// each block walks the 16-tile ring from phase = ((id>>3)+(id>>8)) & 15:
// the 4 co-resident blocks of a CU (ids differing by 8*32 under round-robin
// XCD dispatch) get distinct phases -> one block's softmax-VALU overlaps
// another's MFMA (r14 counters: MfmaUtil+VALUBusy = 82% < 100, no overlap).
//
// KVBLK=128 staging (r14), compute in 64-key sub-blocks. Ks[128][64] linear
// + row-swizzled source; Vd[2][64][80] (stride 80 conflict-free, r11) +
// shared Vones. XCD-aware decode keeps each head's KV on one XCD's L2.
// P = exp2(S~-8) fixed shift; V^T key-permuted -> lane P = PV B-fragment;
// Vones row 0 -> dt=4 MFMA accumulates l.
// ---------------------------------------------------------------------------
__global__ __launch_bounds__(256, 4)
void attn_kernel(const unsigned short* __restrict__ qkv,
                 unsigned short* __restrict__ att)
{
    __shared__ alignas(16) unsigned short Ks[128][64];    // linear (gload_lds dest)
    __shared__ alignas(16) unsigned short Vd[2][64][80];  // [half][d][pos]
    __shared__ alignas(16) unsigned short Vones[16][80];  // row0 = 1.0, rest 0

    const int tid  = threadIdx.x;
    const int lane = tid & 63;
    const int w    = tid >> 6;

    // XCD-aware decode: id = (((b*2 + h_hi)*16 + q)*8 + h_lo)
    const int id  = blockIdx.x;
    const int h   = (id & 7) | (((id >> 7) & 1) << 3);
    const int q0  = ((id >> 3) & 15) * 128;
    const int b   = (id >> 8) & 3;
    const size_t base = (size_t)b * SEQ * QKV_N + (size_t)h * HDIM;

    const int r16 = lane & 15;
    const int g   = lane >> 4;
    const int f7  = r16 & 7;

    // init Vones (row 0 ones, rows 1..15 zero)
    for (int idx = tid; idx < 16 * 80; idx += 256)
        Vones[idx / 80][idx % 80] = (idx < 80) ? 0x3F80 : 0;

    // Q fragments (B operand): col=q=r16, elements d = g*8+j (+32)
    short8 qf[2][2];
    #pragma unroll
    for (int mi = 0; mi < 2; ++mi) {
        const unsigned short* qrow =
            qkv + base + (size_t)(q0 + w * 32 + mi * 16 + r16) * QKV_N;
        qf[mi][0] = *(const short8*)(qrow + g * 8);
        qf[mi][1] = *(const short8*)(qrow + 32 + g * 8);
    }

    f32x4 oacc[2][5] = {};          // [mi][dt]: col q=r16, row d=dt*16+g*4+j; dt=4 -> l

    // K staging: chunk c covers keys c*8..c*8+7; pre-swizzled source group
    const int krow  = lane >> 3;
    const int kGsrc = (lane & 7) ^ (krow & 7);

    // V staging: lane = key (within half); permuted dest column pos(lane)
    const int k5 = lane & 31, khi = lane >> 5;
    const int vpos = ((k5 < 16) ? ((k5 >> 2) * 8 + (k5 & 3))
                                : (((k5 - 16) >> 2) * 8 + 4 + ((k5 - 16) & 3)))
                     + khi * 32;

    // tile-ring stagger: co-resident blocks start at different tiles
    const int phase = ((id >> 3) + (id >> 8)) & 15;

    for (int tt = 0; tt < SEQ / 128; ++tt) {
        const int kt = ((tt + phase) & 15) << 7;

        __syncthreads();   // prev 128-key tile fully consumed
        // --- stage K (128 rows = 16 chunks, 4 per wave)
        #pragma unroll
        for (int c = 0; c < 4; ++c) {
            const int chunk = w * 4 + c;
            const unsigned short* gsrc =
                qkv + base + (size_t)(kt + chunk * 8 + krow) * QKV_N + DIM + kGsrc * 8;
            gload16(gsrc, &Ks[chunk * 8][0]);
        }
        // --- stage V both halves (key = kt+lane and kt+64+lane, same vpos)
        {
            const unsigned short* vsrc =
                qkv + base + (size_t)(kt + lane) * QKV_N + 2 * DIM + w * 16;
            short8 v0 = *(const short8*)(vsrc);
            short8 v1 = *(const short8*)(vsrc + 8);
            #pragma unroll
            for (int i = 0; i < 8; ++i) {
                Vd[0][w * 16 + i][vpos]     = (unsigned short)v0[i];
                Vd[0][w * 16 + 8 + i][vpos] = (unsigned short)v1[i];
            }
            const unsigned short* vsrc1 = vsrc + (size_t)64 * QKV_N;
            short8 v2 = *(const short8*)(vsrc1);
            short8 v3 = *(const short8*)(vsrc1 + 8);
            #pragma unroll
            for (int i = 0; i < 8; ++i) {
                Vd[1][w * 16 + i][vpos]     = (unsigned short)v2[i];
                Vd[1][w * 16 + 8 + i][vpos] = (unsigned short)v3[i];
            }
        }
        __syncthreads();

        // --- two 64-key sub-blocks (identical compute geometry to r13)
        #pragma unroll
        for (int hf = 0; hf < 2; ++hf) {
            // S^T = K Q^T : C[key][q]  (exp2 domain)
            f32x4 sacc[2][4] = {};
            __builtin_amdgcn_s_setprio(1);
            #pragma unroll
            for (int jt = 0; jt < 4; ++jt) {
                const int row = hf * 64 + jt * 16 + r16;
                short8 kf0 = *(const short8*)&Ks[row][(g ^ f7) * 8];
                short8 kf1 = *(const short8*)&Ks[row][((4 + g) ^ f7) * 8];
                sacc[0][jt] = MFMA16(kf0, qf[0][0], sacc[0][jt]);
                sacc[0][jt] = MFMA16(kf1, qf[0][1], sacc[0][jt]);
                sacc[1][jt] = MFMA16(kf0, qf[1][0], sacc[1][jt]);
                sacc[1][jt] = MFMA16(kf1, qf[1][1], sacc[1][jt]);
            }
            __builtin_amdgcn_s_setprio(0);

            // P = exp2(S~ - 8) (fixed shift; no max/branch/rescale)
            short8 pb[2][2];
            #pragma unroll
            for (int mi = 0; mi < 2; ++mi) {
                unsigned pw[8];
                #pragma unroll
                for (int jt = 0; jt < 4; ++jt) {
                    const float p0 = exp2_fast(sacc[mi][jt][0] - 8.f);
                    const float p1 = exp2_fast(sacc[mi][jt][1] - 8.f);
                    const float p2 = exp2_fast(sacc[mi][jt][2] - 8.f);
                    const float p3 = exp2_fast(sacc[mi][jt][3] - 8.f);
                    pw[jt * 2]     = cvt_pk_bf16(p0, p1);
                    pw[jt * 2 + 1] = cvt_pk_bf16(p2, p3);
                }
                union { unsigned u[4]; short8 s; } c0, c1;
                c0.u[0] = pw[0]; c0.u[1] = pw[1]; c0.u[2] = pw[2]; c0.u[3] = pw[3];
                c1.u[0] = pw[4]; c1.u[1] = pw[5]; c1.u[2] = pw[6]; c1.u[3] = pw[7];
                pb[mi][0] = c0.s;   // keys (perm. positions) 0..31 of this half
                pb[mi][1] = c1.s;   // keys 32..63 of this half
            }

            // O^T += V^T P^T from Vd[hf]; l via Vones
            __builtin_amdgcn_s_setprio(1);
            #pragma unroll
            for (int dt = 0; dt < 4; ++dt) {
                short8 vf0 = *(const short8*)&Vd[hf][dt * 16 + r16][g * 8];
                short8 vf1 = *(const short8*)&Vd[hf][dt * 16 + r16][32 + g * 8];
                #pragma unroll
                for (int mi = 0; mi < 2; ++mi) {
                    oacc[mi][dt] = MFMA16(vf0, pb[mi][0], oacc[mi][dt]);
                    oacc[mi][dt] = MFMA16(vf1, pb[mi][1], oacc[mi][dt]);
                }
            }
            {
                short8 vo0 = *(const short8*)&Vones[r16][g * 8];
                short8 vo1 = *(const short8*)&Vones[r16][32 + g * 8];
                #pragma unroll
                for (int mi = 0; mi < 2; ++mi) {
                    oacc[mi][4] = MFMA16(vo0, pb[mi][0], oacc[mi][4]);
                    oacc[mi][4] = MFMA16(vo1, pb[mi][1], oacc[mi][4]);
                }
            }
            __builtin_amdgcn_s_setprio(0);
        }
    }

    // epilogue: O^T[d][q] -> att[q][h*64+d]; l = oacc[mi][4][0] @ lane q (g=0)
    #pragma unroll
    for (int mi = 0; mi < 2; ++mi) {
        const float inv = 1.f / __shfl(oacc[mi][4][0], r16);
        const int q = q0 + w * 32 + mi * 16 + r16;
        unsigned short* dst = att + (size_t)(b * SEQ + q) * DIM + h * HDIM;
        #pragma unroll
        for (int dt = 0; dt < 4; ++dt)
            #pragma unroll
            for (int jr = 0; jr < 4; ++jr)
                dst[dt * 16 + g * 4 + jr] = f2bf(oacc[mi][dt][jr] * inv);
    }
}

// ---------------------------------------------------------------------------
extern "C" void kernel_launch(void* const* d_in, const int* in_sizes, int n_in,
                              void* d_out, int out_size, void* d_ws, size_t ws_size,
                              hipStream_t stream)
{
    const float* x     = (const float*)d_in[0];
    const float* w_qkv = (const float*)d_in[1];
    const float* w_out = (const float*)d_in[2];
    const float* b_out = (const float*)d_in[3];
    float* out = (float*)d_out;

    unsigned short* qkv   = (unsigned short*)d_ws;      // [8192][3072]
    unsigned short* xb    = qkv + 25165824;             // [8192][1024] (aliased w/ att)
    unsigned short* att   = xb;
    unsigned short* wqkvT = qkv + 33554432;             // [3072][1024]
    unsigned short* woutT = qkv + 36700160;             // [1024][1024]

    conv_kernel<<<dim3(ROWS * DIM / 4 / 256), 256, 0, stream>>>(x, xb, ROWS * DIM / 4);
    convT_kernel<<<dim3(QKV_N / 32, DIM / 32), 256, 0, stream>>>(w_qkv, wqkvT, DIM, QKV_N);
    convT_kernel<<<dim3(DIM / 32, DIM / 32), 256, 0, stream>>>(w_out, woutT, DIM, DIM);

    gemm_kernel<false, true><<<dim3(QKV_N / 128, ROWS / 128), 256, 0, stream>>>(
        xb, wqkvT, nullptr, qkv, ROWS, QKV_N, DIM);

    attn_kernel<<<dim3(1024), 256, 0, stream>>>(qkv, att);

    gemm_kernel<true, false><<<dim3(DIM / 128, ROWS / 128), 256, 0, stream>>>(
        att, woutT, b_out, out, ROWS, DIM, DIM);
}

// Round 16
// 179.880 us; speedup vs baseline: 1.1042x; 1.1042x over previous
//
#include <hip/hip_runtime.h>
#include <hip/hip_bf16.h>

typedef __attribute__((ext_vector_type(8))) short short8;
typedef __attribute__((ext_vector_type(4))) short short4v;
typedef __attribute__((ext_vector_type(4))) float f32x4;

#define DIM    1024
#define NHEADS 16
#define HDIM   64
#define SEQ    2048
#define BATCH  4
#define ROWS   8192            // BATCH*SEQ
#define QKV_N  3072            // 3*DIM

// 0.125 * log2(e): folds attention scale AND exp->exp2 conversion into Q
#define QSCALE_LOG2E 0.18033688011112042f

__device__ __forceinline__ unsigned short f2bf(float f) {
    union { float f; unsigned u; } v; v.f = f;
    unsigned u = v.u;
    return (unsigned short)((u + 0x7fffu + ((u >> 16) & 1u)) >> 16);   // RNE
}
__device__ __forceinline__ float exp2_fast(float x) {                // v_exp_f32 = 2^x
    float r;
    asm("v_exp_f32 %0, %1" : "=v"(r) : "v"(x));
    return r;
}
// packed f32x2 -> bf16x2 (lo = a, hi = b); no builtin on gfx950 (T12)
__device__ __forceinline__ unsigned cvt_pk_bf16(float a, float b) {
    unsigned r;
    asm("v_cvt_pk_bf16_f32 %0, %1, %2" : "=v"(r) : "v"(a), "v"(b));
    return r;
}

// async global->LDS, 16B per lane; LDS dest = wave-uniform base + lane*16
__device__ __forceinline__ void gload16(const void* g, void* l) {
    __builtin_amdgcn_global_load_lds(
        (const __attribute__((address_space(1))) unsigned int*)g,
        (__attribute__((address_space(3))) unsigned int*)l, 16, 0, 0);
}

#define MFMA16(a, b, c) __builtin_amdgcn_mfma_f32_16x16x32_bf16(a, b, c, 0, 0, 0)

// ---------------------------------------------------------------------------
// fused prep: [0,8192) conv x->bf16; [8192,11264) transpose w_qkv;
// [11264,12288) transpose w_out. One launch instead of three.
// ---------------------------------------------------------------------------
__device__ __forceinline__ void convT_body(const float* __restrict__ src,
                                           unsigned short* __restrict__ dst,
                                           int R, int C, int bx, int by, int tid)
{
    __shared__ float T[32][33];
    const int r0 = by * 32, c0 = bx * 32;
    const int tc = tid & 31, tr = tid >> 5;   // 32 x 8
    #pragma unroll
    for (int i = 0; i < 4; ++i)
        T[tr + i * 8][tc] = src[(size_t)(r0 + tr + i * 8) * C + c0 + tc];
    __syncthreads();
    #pragma unroll
    for (int i = 0; i < 4; ++i)
        dst[(size_t)(c0 + tr + i * 8) * R + r0 + tc] = f2bf(T[tc][tr + i * 8]);
}

__global__ __launch_bounds__(256)
void prep_kernel(const float* __restrict__ x,     unsigned short* __restrict__ xb,
                 const float* __restrict__ w_qkv, unsigned short* __restrict__ wqkvT,
                 const float* __restrict__ w_out, unsigned short* __restrict__ woutT)
{
    const int id  = blockIdx.x;
    const int tid = threadIdx.x;
    if (id < 8192) {                       // conv: 2097152 float4 elems
        const int i = id * 256 + tid;
        const float4 v = ((const float4*)x)[i];
        short4v o;
        o[0] = (short)f2bf(v.x); o[1] = (short)f2bf(v.y);
        o[2] = (short)f2bf(v.z); o[3] = (short)f2bf(v.w);
        ((short4v*)xb)[i] = o;
    } else if (id < 8192 + 3072) {         // w_qkv [1024][3072] -> [3072][1024]
        const int id2 = id - 8192;
        convT_body(w_qkv, wqkvT, DIM, QKV_N, id2 % (QKV_N / 32), id2 / (QKV_N / 32), tid);
    } else {                               // w_out [1024][1024] -> [1024][1024]
        const int id2 = id - 8192 - 3072;
        convT_body(w_out, woutT, DIM, DIM, id2 % (DIM / 32), id2 / (DIM / 32), tid);
    }
}

// ---------------------------------------------------------------------------
// bf16 MFMA GEMM: C[M,N] = A[M,K] @ BT[N,K]^T (+bias). 128x128 tile, BK=64
// as dual 32-col buffers (m97-proven conflict-free tiling). XCD-chunked
// block swizzle (T1, bijective: nwg % 8 == 0): each XCD gets a contiguous
// 1/8 of the grid -> blocks sharing A-panels co-locate on one L2.
// 256 thr = 4 waves (2x2), 4x4 16x16x32 frags per wave.
// QSCALE: multiply cols < DIM (the Q third of qkv) by 0.125*log2e.
// ---------------------------------------------------------------------------
template<bool WITH_BIAS, bool QSCALE>
__global__ __launch_bounds__(256)
void gemm_kernel(const unsigned short* __restrict__ A,   // [M][K] bf16
                 const unsigned short* __restrict__ BT,  // [N][K] bf16
                 const float* __restrict__ bias,
                 void* __restrict__ Cp, int M, int N, int K)
{
    __shared__ alignas(16) unsigned short LA[2][128][32];
    __shared__ alignas(16) unsigned short LB[2][128][32];

    const int tid  = threadIdx.x;
    const int lane = tid & 63;
    const int w    = tid >> 6;
    const int wr   = w >> 1, wc = w & 1;

    // XCD-chunked swizzle (bijective since nwg % 8 == 0)
    const int nwg = gridDim.x * gridDim.y;
    int fid = blockIdx.y * gridDim.x + blockIdx.x;
    fid = (fid & 7) * (nwg >> 3) + (fid >> 3);
    const int bm = (fid / gridDim.x) * 128;
    const int bn = (fid % gridDim.x) * 128;

    const int r16  = lane & 15, g = lane >> 4;

    f32x4 acc[4][4] = {};

    const int srow = lane >> 2, skg = (lane & 3) * 8;

    for (int k0 = 0; k0 < K; k0 += 64) {
        #pragma unroll
        for (int c = 0; c < 2; ++c) {
            const int chunk = w * 2 + c;            // 8 chunks over 4 waves
            const unsigned short* arow = A  + (size_t)(bm + chunk * 16 + srow) * K + k0 + skg;
            const unsigned short* brow = BT + (size_t)(bn + chunk * 16 + srow) * K + k0 + skg;
            gload16(arow,      &LA[0][chunk * 16][0]);
            gload16(arow + 32, &LA[1][chunk * 16][0]);
            gload16(brow,      &LB[0][chunk * 16][0]);
            gload16(brow + 32, &LB[1][chunk * 16][0]);
        }
        __syncthreads();
        #pragma unroll
        for (int kk = 0; kk < 2; ++kk) {
            short8 af[4], bf_[4];
            #pragma unroll
            for (int i = 0; i < 4; ++i) {
                af[i]  = *(const short8*)&LA[kk][wr * 64 + i * 16 + r16][g * 8];
                bf_[i] = *(const short8*)&LB[kk][wc * 64 + i * 16 + r16][g * 8];
            }
            __builtin_amdgcn_s_setprio(1);
            #pragma unroll
            for (int mi = 0; mi < 4; ++mi)
                #pragma unroll
                for (int ni = 0; ni < 4; ++ni)
                    acc[mi][ni] = MFMA16(af[mi], bf_[ni], acc[mi][ni]);
            __builtin_amdgcn_s_setprio(0);
        }
        __syncthreads();
    }

    #pragma unroll
    for (int mi = 0; mi < 4; ++mi)
        #pragma unroll
        for (int ni = 0; ni < 4; ++ni) {
            const int gcol = bn + wc * 64 + ni * 16 + r16;
            #pragma unroll
            for (int j = 0; j < 4; ++j) {
                const int grow = bm + wr * 64 + mi * 16 + g * 4 + j;
                float v = acc[mi][ni][j];
                if (QSCALE && gcol < DIM) v *= QSCALE_LOG2E;
                if (WITH_BIAS)
                    ((float*)Cp)[(size_t)grow * N + gcol] = v + bias[gcol];
                else
                    ((unsigned short*)Cp)[(size_t)grow * N + gcol] = f2bf(v);
            }
        }
}

// ---------------------------------------------------------------------------
// MFMA flash attention, SWAPPED-operand form, exp2-domain FIXED-SHIFT softmax
// — EXACT r14 form (best measured attn: 85.8 µs; r15 stagger falsified).
// KVBLK=128 staging, compute in 64-key sub-blocks. Ks[128][64] linear +
// row-swizzled source; Vd[2][64][80] (stride 80 conflict-free, r11) + shared
// Vones. XCD-aware decode keeps each head's KV on one XCD's L2 (FETCH
// 139->24.6 MB, r11). P = exp2(S~-8) fixed shift (r13); V^T key-permuted ->
// lane P = PV B-fragment; Vones row 0 -> dt=4 MFMA accumulates l.
// ---------------------------------------------------------------------------
__global__ __launch_bounds__(256, 4)
void attn_kernel(const unsigned short* __restrict__ qkv,
                 unsigned short* __restrict__ att)
{
    __shared__ alignas(16) unsigned short Ks[128][64];    // linear (gload_lds dest)
    __shared__ alignas(16) unsigned short Vd[2][64][80];  // [half][d][pos]
    __shared__ alignas(16) unsigned short Vones[16][80];  // row0 = 1.0, rest 0

    const int tid  = threadIdx.x;
    const int lane = tid & 63;
    const int w    = tid >> 6;

    // XCD-aware decode: id = (((b*2 + h_hi)*16 + q)*8 + h_lo)
    const int id  = blockIdx.x;
    const int h   = (id & 7) | (((id >> 7) & 1) << 3);
    const int q0  = ((id >> 3) & 15) * 128;
    const int b   = (id >> 8) & 3;
    const size_t base = (size_t)b * SEQ * QKV_N + (size_t)h * HDIM;

    const int r16 = lane & 15;
    const int g   = lane >> 4;
    const int f7  = r16 & 7;

    // init Vones (row 0 ones, rows 1..15 zero)
    for (int idx = tid; idx < 16 * 80; idx += 256)
        Vones[idx / 80][idx % 80] = (idx < 80) ? 0x3F80 : 0;

    // Q fragments (B operand): col=q=r16, elements d = g*8+j (+32)
    short8 qf[2][2];
    #pragma unroll
    for (int mi = 0; mi < 2; ++mi) {
        const unsigned short* qrow =
            qkv + base + (size_t)(q0 + w * 32 + mi * 16 + r16) * QKV_N;
        qf[mi][0] = *(const short8*)(qrow + g * 8);
        qf[mi][1] = *(const short8*)(qrow + 32 + g * 8);
    }

    f32x4 oacc[2][5] = {};          // [mi][dt]: col q=r16, row d=dt*16+g*4+j; dt=4 -> l

    // K staging: chunk c covers keys c*8..c*8+7; pre-swizzled source group
    const int krow  = lane >> 3;
    const int kGsrc = (lane & 7) ^ (krow & 7);

    // V staging: lane = key (within half); permuted dest column pos(lane)
    const int k5 = lane & 31, khi = lane >> 5;
    const int vpos = ((k5 < 16) ? ((k5 >> 2) * 8 + (k5 & 3))
                                : (((k5 - 16) >> 2) * 8 + 4 + ((k5 - 16) & 3)))
                     + khi * 32;

    for (int kt = 0; kt < SEQ; kt += 128) {
        __syncthreads();   // prev 128-key tile fully consumed
        // --- stage K (128 rows = 16 chunks, 4 per wave)
        #pragma unroll
        for (int c = 0; c < 4; ++c) {
            const int chunk = w * 4 + c;
            const unsigned short* gsrc =
                qkv + base + (size_t)(kt + chunk * 8 + krow) * QKV_N + DIM + kGsrc * 8;
            gload16(gsrc, &Ks[chunk * 8][0]);
        }
        // --- stage V both halves (key = kt+lane and kt+64+lane, same vpos)
        {
            const unsigned short* vsrc =
                qkv + base + (size_t)(kt + lane) * QKV_N + 2 * DIM + w * 16;
            short8 v0 = *(const short8*)(vsrc);
            short8 v1 = *(const short8*)(vsrc + 8);
            #pragma unroll
            for (int i = 0; i < 8; ++i) {
                Vd[0][w * 16 + i][vpos]     = (unsigned short)v0[i];
                Vd[0][w * 16 + 8 + i][vpos] = (unsigned short)v1[i];
            }
            const unsigned short* vsrc1 = vsrc + (size_t)64 * QKV_N;
            short8 v2 = *(const short8*)(vsrc1);
            short8 v3 = *(const short8*)(vsrc1 + 8);
            #pragma unroll
            for (int i = 0; i < 8; ++i) {
                Vd[1][w * 16 + i][vpos]     = (unsigned short)v2[i];
                Vd[1][w * 16 + 8 + i][vpos] = (unsigned short)v3[i];
            }
        }
        __syncthreads();

        // --- two 64-key sub-blocks (identical compute geometry to r13)
        #pragma unroll
        for (int hf = 0; hf < 2; ++hf) {
            // S^T = K Q^T : C[key][q]  (exp2 domain)
            f32x4 sacc[2][4] = {};
            __builtin_amdgcn_s_setprio(1);
            #pragma unroll
            for (int jt = 0; jt < 4; ++jt) {
                const int row = hf * 64 + jt * 16 + r16;
                short8 kf0 = *(const short8*)&Ks[row][(g ^ f7) * 8];
                short8 kf1 = *(const short8*)&Ks[row][((4 + g) ^ f7) * 8];
                sacc[0][jt] = MFMA16(kf0, qf[0][0], sacc[0][jt]);
                sacc[0][jt] = MFMA16(kf1, qf[0][1], sacc[0][jt]);
                sacc[1][jt] = MFMA16(kf0, qf[1][0], sacc[1][jt]);
                sacc[1][jt] = MFMA16(kf1, qf[1][1], sacc[1][jt]);
            }
            __builtin_amdgcn_s_setprio(0);

            // P = exp2(S~ - 8) (fixed shift; no max/branch/rescale)
            short8 pb[2][2];
            #pragma unroll
            for (int mi = 0; mi < 2; ++mi) {
                unsigned pw[8];
                #pragma unroll
                for (int jt = 0; jt < 4; ++jt) {
                    const float p0 = exp2_fast(sacc[mi][jt][0] - 8.f);
                    const float p1 = exp2_fast(sacc[mi][jt][1] - 8.f);
                    const float p2 = exp2_fast(sacc[mi][jt][2] - 8.f);
                    const float p3 = exp2_fast(sacc[mi][jt][3] - 8.f);
                    pw[jt * 2]     = cvt_pk_bf16(p0, p1);
                    pw[jt * 2 + 1] = cvt_pk_bf16(p2, p3);
                }
                union { unsigned u[4]; short8 s; } c0, c1;
                c0.u[0] = pw[0]; c0.u[1] = pw[1]; c0.u[2] = pw[2]; c0.u[3] = pw[3];
                c1.u[0] = pw[4]; c1.u[1] = pw[5]; c1.u[2] = pw[6]; c1.u[3] = pw[7];
                pb[mi][0] = c0.s;   // keys (perm. positions) 0..31 of this half
                pb[mi][1] = c1.s;   // keys 32..63 of this half
            }

            // O^T += V^T P^T from Vd[hf]; l via Vones
            __builtin_amdgcn_s_setprio(1);
            #pragma unroll
            for (int dt = 0; dt < 4; ++dt) {
                short8 vf0 = *(const short8*)&Vd[hf][dt * 16 + r16][g * 8];
                short8 vf1 = *(const short8*)&Vd[hf][dt * 16 + r16][32 + g * 8];
                #pragma unroll
                for (int mi = 0; mi < 2; ++mi) {
                    oacc[mi][dt] = MFMA16(vf0, pb[mi][0], oacc[mi][dt]);
                    oacc[mi][dt] = MFMA16(vf1, pb[mi][1], oacc[mi][dt]);
                }
            }
            {
                short8 vo0 = *(const short8*)&Vones[r16][g * 8];
                short8 vo1 = *(const short8*)&Vones[r16][32 + g * 8];
                #pragma unroll
                for (int mi = 0; mi < 2; ++mi) {
                    oacc[mi][4] = MFMA16(vo0, pb[mi][0], oacc[mi][4]);
                    oacc[mi][4] = MFMA16(vo1, pb[mi][1], oacc[mi][4]);
                }
            }
            __builtin_amdgcn_s_setprio(0);
        }
    }

    // epilogue: O^T[d][q] -> att[q][h*64+d]; l = oacc[mi][4][0] @ lane q (g=0)
    #pragma unroll
    for (int mi = 0; mi < 2; ++mi) {
        const float inv = 1.f / __shfl(oacc[mi][4][0], r16);
        const int q = q0 + w * 32 + mi * 16 + r16;
        unsigned short* dst = att + (size_t)(b * SEQ + q) * DIM + h * HDIM;
        #pragma unroll
        for (int dt = 0; dt < 4; ++dt)
            #pragma unroll
            for (int jr = 0; jr < 4; ++jr)
                dst[dt * 16 + g * 4 + jr] = f2bf(oacc[mi][dt][jr] * inv);
    }
}

// ---------------------------------------------------------------------------
extern "C" void kernel_launch(void* const* d_in, const int* in_sizes, int n_in,
                              void* d_out, int out_size, void* d_ws, size_t ws_size,
                              hipStream_t stream)
{
    const float* x     = (const float*)d_in[0];
    const float* w_qkv = (const float*)d_in[1];
    const float* w_out = (const float*)d_in[2];
    const float* b_out = (const float*)d_in[3];
    float* out = (float*)d_out;

    unsigned short* qkv   = (unsigned short*)d_ws;      // [8192][3072]
    unsigned short* xb    = qkv + 25165824;             // [8192][1024] (aliased w/ att)
    unsigned short* att   = xb;
    unsigned short* wqkvT = qkv + 33554432;             // [3072][1024]
    unsigned short* woutT = qkv + 36700160;             // [1024][1024]

    prep_kernel<<<dim3(8192 + 3072 + 1024), 256, 0, stream>>>(
        x, xb, w_qkv, wqkvT, w_out, woutT);

    gemm_kernel<false, true><<<dim3(QKV_N / 128, ROWS / 128), 256, 0, stream>>>(
        xb, wqkvT, nullptr, qkv, ROWS, QKV_N, DIM);

    attn_kernel<<<dim3(1024), 256, 0, stream>>>(qkv, att);

    gemm_kernel<true, false><<<dim3(DIM / 128, ROWS / 128), 256, 0, stream>>>(
        att, woutT, b_out, out, ROWS, DIM, DIM);
}

// Round 17
// 174.120 us; speedup vs baseline: 1.1408x; 1.0331x over previous
//
#include <hip/hip_runtime.h>
#include <hip/hip_bf16.h>

typedef __attribute__((ext_vector_type(8))) short short8;
typedef __attribute__((ext_vector_type(4))) short short4v;
typedef __attribute__((ext_vector_type(4))) float f32x4;

#define DIM    1024
#define NHEADS 16
#define HDIM   64
#define SEQ    2048
#define BATCH  4
#define ROWS   8192            // BATCH*SEQ
#define QKV_N  3072            // 3*DIM

// 0.125 * log2(e): folds attention scale AND exp->exp2 conversion into Q
#define QSCALE_LOG2E 0.18033688011112042f

__device__ __forceinline__ unsigned short f2bf(float f) {
    union { float f; unsigned u; } v; v.f = f;
    unsigned u = v.u;
    return (unsigned short)((u + 0x7fffu + ((u >> 16) & 1u)) >> 16);   // RNE
}
__device__ __forceinline__ float exp2_fast(float x) {                // v_exp_f32 = 2^x
    float r;
    asm("v_exp_f32 %0, %1" : "=v"(r) : "v"(x));
    return r;
}
// packed f32x2 -> bf16x2 (lo = a, hi = b); no builtin on gfx950 (T12)
__device__ __forceinline__ unsigned cvt_pk_bf16(float a, float b) {
    unsigned r;
    asm("v_cvt_pk_bf16_f32 %0, %1, %2" : "=v"(r) : "v"(a), "v"(b));
    return r;
}

// async global->LDS, 16B per lane; LDS dest = wave-uniform base + lane*16
__device__ __forceinline__ void gload16(const void* g, void* l) {
    __builtin_amdgcn_global_load_lds(
        (const __attribute__((address_space(1))) unsigned int*)g,
        (__attribute__((address_space(3))) unsigned int*)l, 16, 0, 0);
}

#define MFMA16(a, b, c) __builtin_amdgcn_mfma_f32_16x16x32_bf16(a, b, c, 0, 0, 0)

// ---------------------------------------------------------------------------
// fused prep: [0,8192) conv x->bf16; [8192,11264) transpose w_qkv;
// [11264,12288) transpose w_out. One launch instead of three.
// ---------------------------------------------------------------------------
__device__ __forceinline__ void convT_body(const float* __restrict__ src,
                                           unsigned short* __restrict__ dst,
                                           int R, int C, int bx, int by, int tid)
{
    __shared__ float T[32][33];
    const int r0 = by * 32, c0 = bx * 32;
    const int tc = tid & 31, tr = tid >> 5;   // 32 x 8
    #pragma unroll
    for (int i = 0; i < 4; ++i)
        T[tr + i * 8][tc] = src[(size_t)(r0 + tr + i * 8) * C + c0 + tc];
    __syncthreads();
    #pragma unroll
    for (int i = 0; i < 4; ++i)
        dst[(size_t)(c0 + tr + i * 8) * R + r0 + tc] = f2bf(T[tc][tr + i * 8]);
}

__global__ __launch_bounds__(256)
void prep_kernel(const float* __restrict__ x,     unsigned short* __restrict__ xb,
                 const float* __restrict__ w_qkv, unsigned short* __restrict__ wqkvT,
                 const float* __restrict__ w_out, unsigned short* __restrict__ woutT)
{
    const int id  = blockIdx.x;
    const int tid = threadIdx.x;
    if (id < 8192) {                       // conv: 2097152 float4 elems
        const int i = id * 256 + tid;
        const float4 v = ((const float4*)x)[i];
        short4v o;
        o[0] = (short)f2bf(v.x); o[1] = (short)f2bf(v.y);
        o[2] = (short)f2bf(v.z); o[3] = (short)f2bf(v.w);
        ((short4v*)xb)[i] = o;
    } else if (id < 8192 + 3072) {         // w_qkv [1024][3072] -> [3072][1024]
        const int id2 = id - 8192;
        convT_body(w_qkv, wqkvT, DIM, QKV_N, id2 % (QKV_N / 32), id2 / (QKV_N / 32), tid);
    } else {                               // w_out [1024][1024] -> [1024][1024]
        const int id2 = id - 8192 - 3072;
        convT_body(w_out, woutT, DIM, DIM, id2 % (DIM / 32), id2 / (DIM / 32), tid);
    }
}

// ---------------------------------------------------------------------------
// bf16 MFMA GEMM: C[M,N] = A[M,K] @ BT[N,K]^T (+bias). 128x128 tile, BK=64
// as dual 32-col buffers (m97-proven conflict-free tiling). XCD-chunked
// block swizzle (T1, bijective: nwg % 8 == 0).
// ---------------------------------------------------------------------------
template<bool WITH_BIAS, bool QSCALE>
__global__ __launch_bounds__(256)
void gemm_kernel(const unsigned short* __restrict__ A,   // [M][K] bf16
                 const unsigned short* __restrict__ BT,  // [N][K] bf16
                 const float* __restrict__ bias,
                 void* __restrict__ Cp, int M, int N, int K)
{
    __shared__ alignas(16) unsigned short LA[2][128][32];
    __shared__ alignas(16) unsigned short LB[2][128][32];

    const int tid  = threadIdx.x;
    const int lane = tid & 63;
    const int w    = tid >> 6;
    const int wr   = w >> 1, wc = w & 1;

    // XCD-chunked swizzle (bijective since nwg % 8 == 0)
    const int nwg = gridDim.x * gridDim.y;
    int fid = blockIdx.y * gridDim.x + blockIdx.x;
    fid = (fid & 7) * (nwg >> 3) + (fid >> 3);
    const int bm = (fid / gridDim.x) * 128;
    const int bn = (fid % gridDim.x) * 128;

    const int r16  = lane & 15, g = lane >> 4;

    f32x4 acc[4][4] = {};

    const int srow = lane >> 2, skg = (lane & 3) * 8;

    for (int k0 = 0; k0 < K; k0 += 64) {
        #pragma unroll
        for (int c = 0; c < 2; ++c) {
            const int chunk = w * 2 + c;            // 8 chunks over 4 waves
            const unsigned short* arow = A  + (size_t)(bm + chunk * 16 + srow) * K + k0 + skg;
            const unsigned short* brow = BT + (size_t)(bn + chunk * 16 + srow) * K + k0 + skg;
            gload16(arow,      &LA[0][chunk * 16][0]);
            gload16(arow + 32, &LA[1][chunk * 16][0]);
            gload16(brow,      &LB[0][chunk * 16][0]);
            gload16(brow + 32, &LB[1][chunk * 16][0]);
        }
        __syncthreads();
        #pragma unroll
        for (int kk = 0; kk < 2; ++kk) {
            short8 af[4], bf_[4];
            #pragma unroll
            for (int i = 0; i < 4; ++i) {
                af[i]  = *(const short8*)&LA[kk][wr * 64 + i * 16 + r16][g * 8];
                bf_[i] = *(const short8*)&LB[kk][wc * 64 + i * 16 + r16][g * 8];
            }
            __builtin_amdgcn_s_setprio(1);
            #pragma unroll
            for (int mi = 0; mi < 4; ++mi)
                #pragma unroll
                for (int ni = 0; ni < 4; ++ni)
                    acc[mi][ni] = MFMA16(af[mi], bf_[ni], acc[mi][ni]);
            __builtin_amdgcn_s_setprio(0);
        }
        __syncthreads();
    }

    #pragma unroll
    for (int mi = 0; mi < 4; ++mi)
        #pragma unroll
        for (int ni = 0; ni < 4; ++ni) {
            const int gcol = bn + wc * 64 + ni * 16 + r16;
            #pragma unroll
            for (int j = 0; j < 4; ++j) {
                const int grow = bm + wr * 64 + mi * 16 + g * 4 + j;
                float v = acc[mi][ni][j];
                if (QSCALE && gcol < DIM) v *= QSCALE_LOG2E;
                if (WITH_BIAS)
                    ((float*)Cp)[(size_t)grow * N + gcol] = v + bias[gcol];
                else
                    ((unsigned short*)Cp)[(size_t)grow * N + gcol] = f2bf(v);
            }
        }
}

// ---------------------------------------------------------------------------
// MFMA flash attention, SWAPPED-operand form, exp2-domain FIXED-SHIFT softmax.
// Round-17: QBLK=256 — each wave carries FOUR 16-q fragments (mi=0..3), so
// the same K/V LDS bytes feed 2x the MFMA (per-CU LDS-read traffic and
// staging work halve vs QBLK=128; inverse of r12's falsified direction).
// Grid 512 = 2 blocks/CU; __launch_bounds__(256,2) -> 256-VGPR budget
// (liveness ~210: oacc 80 + qf 32 + sacc 64 + misc). WRITE_SIZE = spill
// tripwire. All layouts identical to r14/r16 (proven conflict-free).
//
// KVBLK=128 staging, compute in 64-key sub-blocks. Ks[128][64] linear +
// row-swizzled source; Vd[2][64][80] + shared Vones. XCD decode keeps each
// head's KV on one XCD's L2. P = exp2(S~-8) fixed shift; V^T key-permuted ->
// lane P = PV B-fragment; Vones row 0 -> dt=4 MFMA accumulates l.
// ---------------------------------------------------------------------------
__global__ __launch_bounds__(256, 2)
void attn_kernel(const unsigned short* __restrict__ qkv,
                 unsigned short* __restrict__ att)
{
    __shared__ alignas(16) unsigned short Ks[128][64];    // linear (gload_lds dest)
    __shared__ alignas(16) unsigned short Vd[2][64][80];  // [half][d][pos]
    __shared__ alignas(16) unsigned short Vones[16][80];  // row0 = 1.0, rest 0

    const int tid  = threadIdx.x;
    const int lane = tid & 63;
    const int w    = tid >> 6;

    // XCD-aware decode: id = (((b*2 + h_hi)*8 + q)*8 + h_lo), 512 blocks
    const int id  = blockIdx.x;
    const int h   = (id & 7) | (((id >> 6) & 1) << 3);
    const int q0  = ((id >> 3) & 7) * 256;
    const int b   = (id >> 7) & 3;
    const size_t base = (size_t)b * SEQ * QKV_N + (size_t)h * HDIM;

    const int r16 = lane & 15;
    const int g   = lane >> 4;
    const int f7  = r16 & 7;

    // init Vones (row 0 ones, rows 1..15 zero)
    for (int idx = tid; idx < 16 * 80; idx += 256)
        Vones[idx / 80][idx % 80] = (idx < 80) ? 0x3F80 : 0;

    // Q fragments (B operand): col=q=r16, elements d = g*8+j (+32)
    // wave w owns q rows [w*64, w*64+64) as 4 fragments
    short8 qf[4][2];
    #pragma unroll
    for (int mi = 0; mi < 4; ++mi) {
        const unsigned short* qrow =
            qkv + base + (size_t)(q0 + w * 64 + mi * 16 + r16) * QKV_N;
        qf[mi][0] = *(const short8*)(qrow + g * 8);
        qf[mi][1] = *(const short8*)(qrow + 32 + g * 8);
    }

    f32x4 oacc[4][5] = {};          // [mi][dt]: col q=r16, row d=dt*16+g*4+j; dt=4 -> l

    // K staging: chunk c covers keys c*8..c*8+7; pre-swizzled source group
    const int krow  = lane >> 3;
    const int kGsrc = (lane & 7) ^ (krow & 7);

    // V staging: lane = key (within half); permuted dest column pos(lane)
    const int k5 = lane & 31, khi = lane >> 5;
    const int vpos = ((k5 < 16) ? ((k5 >> 2) * 8 + (k5 & 3))
                                : (((k5 - 16) >> 2) * 8 + 4 + ((k5 - 16) & 3)))
                     + khi * 32;

    for (int kt = 0; kt < SEQ; kt += 128) {
        __syncthreads();   // prev 128-key tile fully consumed
        // --- stage K (128 rows = 16 chunks, 4 per wave)
        #pragma unroll
        for (int c = 0; c < 4; ++c) {
            const int chunk = w * 4 + c;
            const unsigned short* gsrc =
                qkv + base + (size_t)(kt + chunk * 8 + krow) * QKV_N + DIM + kGsrc * 8;
            gload16(gsrc, &Ks[chunk * 8][0]);
        }
        // --- stage V both halves (key = kt+lane and kt+64+lane, same vpos)
        {
            const unsigned short* vsrc =
                qkv + base + (size_t)(kt + lane) * QKV_N + 2 * DIM + w * 16;
            short8 v0 = *(const short8*)(vsrc);
            short8 v1 = *(const short8*)(vsrc + 8);
            #pragma unroll
            for (int i = 0; i < 8; ++i) {
                Vd[0][w * 16 + i][vpos]     = (unsigned short)v0[i];
                Vd[0][w * 16 + 8 + i][vpos] = (unsigned short)v1[i];
            }
            const unsigned short* vsrc1 = vsrc + (size_t)64 * QKV_N;
            short8 v2 = *(const short8*)(vsrc1);
            short8 v3 = *(const short8*)(vsrc1 + 8);
            #pragma unroll
            for (int i = 0; i < 8; ++i) {
                Vd[1][w * 16 + i][vpos]     = (unsigned short)v2[i];
                Vd[1][w * 16 + 8 + i][vpos] = (unsigned short)v3[i];
            }
        }
        __syncthreads();

        // --- two 64-key sub-blocks
        #pragma unroll
        for (int hf = 0; hf < 2; ++hf) {
            // S^T = K Q^T : C[key][q]  (exp2 domain)
            f32x4 sacc[4][4] = {};      // [mi][jt]
            __builtin_amdgcn_s_setprio(1);
            #pragma unroll
            for (int jt = 0; jt < 4; ++jt) {
                const int row = hf * 64 + jt * 16 + r16;
                short8 kf0 = *(const short8*)&Ks[row][(g ^ f7) * 8];
                short8 kf1 = *(const short8*)&Ks[row][((4 + g) ^ f7) * 8];
                #pragma unroll
                for (int mi = 0; mi < 4; ++mi) {
                    sacc[mi][jt] = MFMA16(kf0, qf[mi][0], sacc[mi][jt]);
                    sacc[mi][jt] = MFMA16(kf1, qf[mi][1], sacc[mi][jt]);
                }
            }
            __builtin_amdgcn_s_setprio(0);

            // P = exp2(S~ - 8) (fixed shift; no max/branch/rescale)
            short8 pb[4][2];
            #pragma unroll
            for (int mi = 0; mi < 4; ++mi) {
                unsigned pw[8];
                #pragma unroll
                for (int jt = 0; jt < 4; ++jt) {
                    const float p0 = exp2_fast(sacc[mi][jt][0] - 8.f);
                    const float p1 = exp2_fast(sacc[mi][jt][1] - 8.f);
                    const float p2 = exp2_fast(sacc[mi][jt][2] - 8.f);
                    const float p3 = exp2_fast(sacc[mi][jt][3] - 8.f);
                    pw[jt * 2]     = cvt_pk_bf16(p0, p1);
                    pw[jt * 2 + 1] = cvt_pk_bf16(p2, p3);
                }
                union { unsigned u[4]; short8 s; } c0, c1;
                c0.u[0] = pw[0]; c0.u[1] = pw[1]; c0.u[2] = pw[2]; c0.u[3] = pw[3];
                c1.u[0] = pw[4]; c1.u[1] = pw[5]; c1.u[2] = pw[6]; c1.u[3] = pw[7];
                pb[mi][0] = c0.s;   // keys (perm. positions) 0..31 of this half
                pb[mi][1] = c1.s;   // keys 32..63 of this half
            }

            // O^T += V^T P^T from Vd[hf]; l via Vones
            __builtin_amdgcn_s_setprio(1);
            #pragma unroll
            for (int dt = 0; dt < 4; ++dt) {
                short8 vf0 = *(const short8*)&Vd[hf][dt * 16 + r16][g * 8];
                short8 vf1 = *(const short8*)&Vd[hf][dt * 16 + r16][32 + g * 8];
                #pragma unroll
                for (int mi = 0; mi < 4; ++mi) {
                    oacc[mi][dt] = MFMA16(vf0, pb[mi][0], oacc[mi][dt]);
                    oacc[mi][dt] = MFMA16(vf1, pb[mi][1], oacc[mi][dt]);
                }
            }
            {
                short8 vo0 = *(const short8*)&Vones[r16][g * 8];
                short8 vo1 = *(const short8*)&Vones[r16][32 + g * 8];
                #pragma unroll
                for (int mi = 0; mi < 4; ++mi) {
                    oacc[mi][4] = MFMA16(vo0, pb[mi][0], oacc[mi][4]);
                    oacc[mi][4] = MFMA16(vo1, pb[mi][1], oacc[mi][4]);
                }
            }
            __builtin_amdgcn_s_setprio(0);
        }
    }

    // epilogue: O^T[d][q] -> att[q][h*64+d]; l = oacc[mi][4][0] @ lane q (g=0)
    #pragma unroll
    for (int mi = 0; mi < 4; ++mi) {
        const float inv = 1.f / __shfl(oacc[mi][4][0], r16);
        const int q = q0 + w * 64 + mi * 16 + r16;
        unsigned short* dst = att + (size_t)(b * SEQ + q) * DIM + h * HDIM;
        #pragma unroll
        for (int dt = 0; dt < 4; ++dt)
            #pragma unroll
            for (int jr = 0; jr < 4; ++jr)
                dst[dt * 16 + g * 4 + jr] = f2bf(oacc[mi][dt][jr] * inv);
    }
}

// ---------------------------------------------------------------------------
extern "C" void kernel_launch(void* const* d_in, const int* in_sizes, int n_in,
                              void* d_out, int out_size, void* d_ws, size_t ws_size,
                              hipStream_t stream)
{
    const float* x     = (const float*)d_in[0];
    const float* w_qkv = (const float*)d_in[1];
    const float* w_out = (const float*)d_in[2];
    const float* b_out = (const float*)d_in[3];
    float* out = (float*)d_out;

    unsigned short* qkv   = (unsigned short*)d_ws;      // [8192][3072]
    unsigned short* xb    = qkv + 25165824;             // [8192][1024] (aliased w/ att)
    unsigned short* att   = xb;
    unsigned short* wqkvT = qkv + 33554432;             // [3072][1024]
    unsigned short* woutT = qkv + 36700160;             // [1024][1024]

    prep_kernel<<<dim3(8192 + 3072 + 1024), 256, 0, stream>>>(
        x, xb, w_qkv, wqkvT, w_out, woutT);

    gemm_kernel<false, true><<<dim3(QKV_N / 128, ROWS / 128), 256, 0, stream>>>(
        xb, wqkvT, nullptr, qkv, ROWS, QKV_N, DIM);

    attn_kernel<<<dim3(512), 256, 0, stream>>>(qkv, att);

    gemm_kernel<true, false><<<dim3(DIM / 128, ROWS / 128), 256, 0, stream>>>(
        att, woutT, b_out, out, ROWS, DIM, DIM);
}